// Round 9
// baseline (477.625 us; speedup 1.0000x reference)
//
#include <hip/hip_runtime.h>
#include <hip/hip_bf16.h>
#include <stdint.h>

#define BATCH 16
#define CIN   256
#define HH    112
#define WW    112
#define GROUPS 2
#define CG    128   // cin per group
#define COG   128   // cout per group
#define CK    32    // cin chunk per K-step

typedef __bf16 bf16x8 __attribute__((ext_vector_type(8)));
typedef float  f32x4  __attribute__((ext_vector_type(4)));

// ---- workspace layout ----
#define WB_BYTES   (GROUPS*3*3*COG*CG*2)        // 589824
#define ZBUF_OFF   WB_BYTES
#define ZBUF_BYTES 65536
#define XB_OFF     (ZBUF_OFF + ZBUF_BYTES)      // 655360
#define XB_BYTES   ((size_t)BATCH*HH*WW*CIN*2)  // 102760448
#define WS_NEED    ((size_t)XB_OFF + XB_BYTES)  // 103415808

__device__ inline void load_lds16(const void* g, void* l) {
    __builtin_amdgcn_global_load_lds(
        (const __attribute__((address_space(1))) void*)g,
        (__attribute__((address_space(3))) void*)l, 16, 0, 0);
}

// ---- pre-pass 1: weights OIHW fp32 -> [g][kh][kw][cout][cin] bf16 ----
__global__ __launch_bounds__(256) void k_wcvt(const float* __restrict__ w,
                                              ushort* __restrict__ wb) {
    int i = blockIdx.x * 256 + threadIdx.x;   // 294912 total
    int ci = i & 127;
    int t  = i >> 7;
    int co = t & 127;
    t >>= 7;                                  // t = g*9 + kh*3 + kw
    int kw = t % 3; t /= 3;
    int kh = t % 3;
    int g  = t / 3;
    int src = (((g*COG + co)*CG + ci)*3 + kh)*3 + kw;
    __hip_bfloat16 v = __float2bfloat16(w[src]);
    wb[i] = *reinterpret_cast<ushort*>(&v);
}

// ---- pre-pass 2: x NCHW fp32 -> NHWC bf16 (LDS transpose) ----
#define XPAD 113
__global__ __launch_bounds__(256) void k_xcvt(const float* __restrict__ x,
                                              ushort* __restrict__ xb) {
    __shared__ float tile[64 * XPAD];
    int bid = blockIdx.x;            // 16*112*4 = 7168
    int cc  = bid & 3;               // chunk of 64 channels
    int h   = (bid >> 2) % HH;
    int b   = bid / (4 * HH);
    int tid = threadIdx.x;

    const float* src = x + ((size_t)(b*CIN + cc*64) * HH + h) * WW;
    for (int tt = tid; tt < 64*28; tt += 256) {
        int c = tt / 28, v = tt % 28;
        float4 f = *reinterpret_cast<const float4*>(src + (size_t)c*HH*WW + v*4);
        float* d = &tile[c*XPAD + v*4];
        d[0]=f.x; d[1]=f.y; d[2]=f.z; d[3]=f.w;
    }
    __syncthreads();

    if (tid < 224) {
        int w = tid >> 1, half = tid & 1;
        ushort o[32];
#pragma unroll
        for (int j = 0; j < 32; ++j) {
            __hip_bfloat16 v = __float2bfloat16(tile[(half*32 + j)*XPAD + w]);
            o[j] = *reinterpret_cast<ushort*>(&v);
        }
        ushort* dst = xb + (((size_t)(b*HH + h)*WW + w)*CIN + cc*64 + half*32);
        const uint4* o4 = reinterpret_cast<const uint4*>(o);
        uint4* d4 = reinterpret_cast<uint4*>(dst);
        d4[0]=o4[0]; d4[1]=o4[1]; d4[2]=o4[2]; d4[3]=o4[3];
    }
}

// ---- stage one 3-tap weight group into LDS (swizzled source) ----
__device__ inline void stage_w3(const ushort* __restrict__ wb, ushort* dstbuf,
                                int g, int tap_base, int cin, int wave, int lane) {
    int co = wave*16 + (lane >> 2);
    int ts = (lane & 3) ^ ((lane >> 3) & 3);
#pragma unroll
    for (int i = 0; i < 3; ++i) {
        const ushort* src = wb + (((size_t)(g*9 + tap_base + i)*COG + co)*CG + cin + ts*8);
        load_lds16(src, dstbuf + (i*COG + wave*16)*CK);
    }
}

// issue 7 global x-fragment loads for tap (KH2,KW2) into register buffer XN.
// address select (zero page) happens BEFORE issue -> no early vmcnt waits.
#define XISSUE(XN, KH2, KW2, CINV)                                          \
  {                                                                         \
    int h_ = oh0 + wr + (KH2) - 1;                                          \
    const ushort* rowp_ = (h_ >= 0 && h_ < HH)                              \
        ? xb + ((size_t)(b*HH + h_)*WW)*CIN + coffb + (CINV)                \
        : zb;                                                               \
    _Pragma("unroll")                                                       \
    for (int n_ = 0; n_ < 7; ++n_) {                                        \
      const ushort* a_ = rowp_ + (n_*16 + l15 + (KW2) - 1)*CIN;             \
      if ((KW2) == 0 && n_ == 0) a_ = (l15 == 0)  ? zb + lane*8 : a_;       \
      if ((KW2) == 2 && n_ == 6) a_ = (l15 == 15) ? zb + lane*8 : a_;       \
      XN[n_] = *reinterpret_cast<const bf16x8*>(a_);                        \
    }                                                                       \
  }

// issue 4 wf LDS reads for tap TAP2 into WN (r3-verified swizzled path)
#define WISSUE(WN, WCUR, TAP2)                                              \
  {                                                                         \
    const ushort* ab_ = (WCUR) + ((TAP2)*COG + wm*64 + l15)*CK + sA*8;      \
    _Pragma("unroll")                                                       \
    for (int u_ = 0; u_ < 4; ++u_)                                          \
      WN[u_] = *reinterpret_cast<const bf16x8*>(ab_ + u_*16*CK);            \
  }

// 28 MFMAs on current-tap registers; sched_barrier pins the prefetch issues
// above the cluster (prevents the compiler sinking loads to their use).
#define MF(XC, WC)                                                          \
    __builtin_amdgcn_sched_barrier(0);                                      \
    __builtin_amdgcn_s_setprio(1);                                          \
    _Pragma("unroll")                                                       \
    for (int u_ = 0; u_ < 4; ++u_)                                          \
      _Pragma("unroll")                                                     \
      for (int i_ = 0; i_ < 7; ++i_)                                        \
        acc[i_][u_] = __builtin_amdgcn_mfma_f32_16x16x32_bf16(              \
            XC[i_], WC[u_], acc[i_][u_], 0, 0, 0);                          \
    __builtin_amdgcn_s_setprio(0);

// one cin-chunk: 9 taps, fully unrolled, 1-tap-deep register prefetch of both
// operands; barrier only at chunk end (publishes WNXT). vmcnt(7) leaves the
// next chunk's tap-0 x batch in flight but drains the w-stages.
#define CHUNK(XA, XB, CIN_, CINN_, WCUR, WNXT, DONEXT)                      \
  {                                                                         \
    WISSUE(wfA, WCUR, 0)                                                    \
    XISSUE(XB, 0, 1, CIN_) WISSUE(wfB, WCUR, 1)                             \
      stage_w3(wb, WNXT,             g, 0, CINN_, wave, lane); MF(XA, wfA)  \
    XISSUE(XA, 0, 2, CIN_) WISSUE(wfA, WCUR, 2)                             \
      stage_w3(wb, WNXT + 3*COG*CK,  g, 3, CINN_, wave, lane); MF(XB, wfB)  \
    XISSUE(XB, 1, 0, CIN_) WISSUE(wfB, WCUR, 3)                             \
      stage_w3(wb, WNXT + 6*COG*CK,  g, 6, CINN_, wave, lane); MF(XA, wfA)  \
    XISSUE(XA, 1, 1, CIN_) WISSUE(wfA, WCUR, 4) MF(XB, wfB)                 \
    XISSUE(XB, 1, 2, CIN_) WISSUE(wfB, WCUR, 5) MF(XA, wfA)                 \
    XISSUE(XA, 2, 0, CIN_) WISSUE(wfA, WCUR, 6) MF(XB, wfB)                 \
    XISSUE(XB, 2, 1, CIN_) WISSUE(wfB, WCUR, 7) MF(XA, wfA)                 \
    XISSUE(XA, 2, 2, CIN_) WISSUE(wfA, WCUR, 8) MF(XB, wfB)                 \
    if (DONEXT) { XISSUE(XB, 0, 0, CINN_) }                                 \
    MF(XA, wfA)                                                             \
    asm volatile("s_waitcnt vmcnt(7)" ::: "memory");                        \
    __builtin_amdgcn_s_barrier();                                           \
  }

// ---- main kernel: implicit-GEMM grouped conv, register-prefetched operands ----
// x-fragments: global->reg straight from NHWC xb (contiguous 16B/lane, 1KB/
// wave coalesced, L1-resident working set ~28.7KB/kh). w: LDS 9-tap dbuf
// (r3-verified swizzle, conflicts==0). Both operands prefetched one full tap
// ahead -> the MFMA cluster covers the load latency; LDS pipe load drops 7/11.
// 4 barriers total. Epilogue = r7-verified operand-swap dwordx4 stores.
__global__ __launch_bounds__(512, 2) void k_conv(const ushort* __restrict__ xb,
                                                 const ushort* __restrict__ wb,
                                                 const float* __restrict__ bias,
                                                 float* __restrict__ out,
                                                 const ushort* __restrict__ zb) {
    __shared__ __align__(16) ushort wsb[2][9*COG*CK];    // 2 x 73728 B

    int orig = (blockIdx.x & 7) * 112 + (blockIdx.x >> 3);   // XCD swizzle
    int g   = orig / 448;
    int r   = orig % 448;
    int b   = r / 28;
    int q   = r % 28;
    int oh0 = q * 4;

    int tid  = threadIdx.x;
    int wave = tid >> 6;
    int lane = tid & 63;
    int wm   = wave >> 2;          // cout half (0..1), 64 couts
    int wr   = wave & 3;           // output row within quad (0..3)
    int l15  = lane & 15;
    int lk   = lane >> 4;
    int sA   = lk ^ ((l15 >> 1) & 3);    // weight-read slot
    int coffb = g*CG + lk*8;             // channel base within the 256-ch dim

    // bias per lane: co = g*COG + wm*64 + u*16 + l15
    float bvreg[4];
#pragma unroll
    for (int u = 0; u < 4; ++u)
        bvreg[u] = bias[g*COG + wm*64 + u*16 + l15];

    f32x4 acc[7][4];
#pragma unroll
    for (int i = 0; i < 7; ++i)
#pragma unroll
        for (int u = 0; u < 4; ++u) acc[i][u] = f32x4{0.f,0.f,0.f,0.f};

    bf16x8 xf0[7], xf1[7], wfA[4], wfB[4];

    // prologue: x(chunk0,tap0) -> xf0; stage all 9 w taps of chunk0; drain once
    XISSUE(xf0, 0, 0, 0)
    stage_w3(wb, wsb[0],             g, 0, 0, wave, lane);
    stage_w3(wb, wsb[0] + 3*COG*CK,  g, 3, 0, wave, lane);
    stage_w3(wb, wsb[0] + 6*COG*CK,  g, 6, 0, wave, lane);
    asm volatile("s_waitcnt vmcnt(0)" ::: "memory");
    __builtin_amdgcn_s_barrier();

    CHUNK(xf0, xf1, 0*CK, 1*CK, wsb[0], wsb[1], true)
    CHUNK(xf1, xf0, 1*CK, 2*CK, wsb[1], wsb[0], true)
    CHUNK(xf0, xf1, 2*CK, 3*CK, wsb[0], wsb[1], true)
    CHUNK(xf1, xf0, 3*CK, 0*CK, wsb[1], wsb[0], false)

    // epilogue (r7-verified): acc[i][u] -> 28 dwordx4 stores, 4 contiguous px
    int oh = oh0 + wr;
#pragma unroll
    for (int u = 0; u < 4; ++u) {
        int co = g*COG + wm*64 + u*16 + l15;
        float bv = bvreg[u];
        float* obase = out + (((size_t)(b*CIN + co)*HH + oh)*WW + lk*4);
#pragma unroll
        for (int i = 0; i < 7; ++i) {
            f32x4 v;
            v[0] = acc[i][u][0] + bv;
            v[1] = acc[i][u][1] + bv;
            v[2] = acc[i][u][2] + bv;
            v[3] = acc[i][u][3] + bv;
            *reinterpret_cast<f32x4*>(obase + i*16) = v;
        }
    }
}

// ---- fallback: direct fp32 conv (used only if ws is too small) ----
__global__ __launch_bounds__(128) void k_direct(const float* __restrict__ x,
                                                const float* __restrict__ w,
                                                const float* __restrict__ bias,
                                                float* __restrict__ out) {
    int bid = blockIdx.x;          // B*Cout*H
    int oh  = bid % HH;
    int t   = bid / HH;
    int co  = t % CIN;
    int b   = t / CIN;
    int ow  = threadIdx.x;
    if (ow >= WW) return;
    int g = co / COG;
    float s = bias[co];
    const float* wp = w + (size_t)co*CG*9;
    const float* xp = x + ((size_t)b*CIN + g*CG)*HH*WW;
    for (int ci = 0; ci < CG; ++ci) {
        const float* xr = xp + (size_t)ci*HH*WW;
        const float* wr_ = wp + ci*9;
#pragma unroll
        for (int kh = 0; kh < 3; ++kh) {
            int ih = oh + kh - 1;
            if (ih < 0 || ih >= HH) continue;
#pragma unroll
            for (int kw = 0; kw < 3; ++kw) {
                int iw = ow + kw - 1;
                if (iw < 0 || iw >= WW) continue;
                s += xr[ih*WW + iw] * wr_[kh*3 + kw];
            }
        }
    }
    out[(((size_t)b*CIN + co)*HH + oh)*WW + ow] = s;
}

extern "C" void kernel_launch(void* const* d_in, const int* in_sizes, int n_in,
                              void* d_out, int out_size, void* d_ws, size_t ws_size,
                              hipStream_t stream) {
    const float* x    = (const float*)d_in[0];
    const float* w    = (const float*)d_in[1];
    const float* bias = (const float*)d_in[2];
    float* out        = (float*)d_out;

    if (ws_size >= WS_NEED) {
        ushort* wb   = (ushort*)d_ws;
        ushort* zb   = (ushort*)((char*)d_ws + ZBUF_OFF);
        ushort* xbuf = (ushort*)((char*)d_ws + XB_OFF);
        hipMemsetAsync(zb, 0, ZBUF_BYTES, stream);
        k_wcvt<<<1152, 256, 0, stream>>>(w, wb);
        k_xcvt<<<BATCH*HH*4, 256, 0, stream>>>(x, xbuf);
        k_conv<<<896, 512, 0, stream>>>(xbuf, wb, bias, out, zb);
    } else {
        k_direct<<<BATCH*CIN*HH, 128, 0, stream>>>(x, w, bias, out);
    }
}

// Round 10
// 243.010 us; speedup vs baseline: 1.9655x; 1.9655x over previous
//
#include <hip/hip_runtime.h>
#include <hip/hip_bf16.h>
#include <stdint.h>

#define BATCH 16
#define CIN   256
#define HH    112
#define WW    112
#define GROUPS 2
#define CG    128   // cin per group
#define COG   128   // cout per group
#define CK    32    // cin chunk per K-step
#define NCHUNK 4

typedef __bf16 bf16x8 __attribute__((ext_vector_type(8)));
typedef float  f32x4  __attribute__((ext_vector_type(4)));

// ---- workspace layout ----
#define WB_BYTES   (GROUPS*3*3*COG*CG*2)        // 589824
#define ZBUF_OFF   WB_BYTES
#define ZBUF_BYTES 8192
#define XB_OFF     (ZBUF_OFF + ZBUF_BYTES)      // 598016
#define XB_BYTES   ((size_t)BATCH*HH*WW*CIN*2)  // 102760448
#define WS_NEED    ((size_t)XB_OFF + XB_BYTES)  // 103358464

__device__ inline void load_lds16(const void* g, void* l) {
    __builtin_amdgcn_global_load_lds(
        (const __attribute__((address_space(1))) void*)g,
        (__attribute__((address_space(3))) void*)l, 16, 0, 0);
}

// ---- pre-pass 1: weights OIHW fp32 -> [g][kh][kw][cout][cin] bf16 ----
__global__ __launch_bounds__(256) void k_wcvt(const float* __restrict__ w,
                                              ushort* __restrict__ wb) {
    int i = blockIdx.x * 256 + threadIdx.x;   // 294912 total
    int ci = i & 127;
    int t  = i >> 7;
    int co = t & 127;
    t >>= 7;                                  // t = g*9 + kh*3 + kw
    int kw = t % 3; t /= 3;
    int kh = t % 3;
    int g  = t / 3;
    int src = (((g*COG + co)*CG + ci)*3 + kh)*3 + kw;
    __hip_bfloat16 v = __float2bfloat16(w[src]);
    wb[i] = *reinterpret_cast<ushort*>(&v);
}

// ---- pre-pass 2: x NCHW fp32 -> NHWC bf16 (LDS transpose) ----
#define XPAD 113
__global__ __launch_bounds__(256) void k_xcvt(const float* __restrict__ x,
                                              ushort* __restrict__ xb) {
    __shared__ float tile[64 * XPAD];
    int bid = blockIdx.x;            // 16*112*4 = 7168
    int cc  = bid & 3;               // chunk of 64 channels
    int h   = (bid >> 2) % HH;
    int b   = bid / (4 * HH);
    int tid = threadIdx.x;

    const float* src = x + ((size_t)(b*CIN + cc*64) * HH + h) * WW;
    for (int tt = tid; tt < 64*28; tt += 256) {
        int c = tt / 28, v = tt % 28;
        float4 f = *reinterpret_cast<const float4*>(src + (size_t)c*HH*WW + v*4);
        float* d = &tile[c*XPAD + v*4];
        d[0]=f.x; d[1]=f.y; d[2]=f.z; d[3]=f.w;
    }
    __syncthreads();

    if (tid < 224) {
        int w = tid >> 1, half = tid & 1;
        ushort o[32];
#pragma unroll
        for (int j = 0; j < 32; ++j) {
            __hip_bfloat16 v = __float2bfloat16(tile[(half*32 + j)*XPAD + w]);
            o[j] = *reinterpret_cast<ushort*>(&v);
        }
        ushort* dst = xb + (((size_t)(b*HH + h)*WW + w)*CIN + cc*64 + half*32);
        const uint4* o4 = reinterpret_cast<const uint4*>(o);
        uint4* d4 = reinterpret_cast<uint4*>(dst);
        d4[0]=o4[0]; d4[1]=o4[1]; d4[2]=o4[2]; d4[3]=o4[3];
    }
}

// ---- stage all 9 weight taps of one cin-chunk (swizzled source) ----
__device__ inline void stage_w_all(const ushort* __restrict__ wb, ushort* dstbuf,
                                   int g, int cin, int wave, int lane) {
    int co = wave*16 + (lane >> 2);
    int ts = (lane & 3) ^ ((lane >> 3) & 3);
#pragma unroll
    for (int tap = 0; tap < 9; ++tap) {
        const ushort* src = wb + (((size_t)(g*9 + tap)*COG + co)*CG + cin + ts*8);
        load_lds16(src, dstbuf + (tap*COG + wave*16)*CK);
    }
}

// ---- stage 6 halo x rows of one cin-chunk (swizzled source) ----
__device__ inline void stage_x(const ushort* __restrict__ xb, ushort* dst,
                               const ushort* __restrict__ zbuf,
                               int b, int g, int oh0, int cin, int wave, int lane) {
    int qv = lane >> 2;
    for (int t = wave; t < 42; t += 8) {
        int rr = t / 7, ii = t % 7;
        int h    = oh0 - 1 + rr;
        int w_in = ii*16 + qv;
        int ts   = (lane & 3) ^ (((2*rr + 1 + qv) >> 1) & 3);
        const ushort* src = (h >= 0 && h < HH)
            ? xb + (((size_t)(b*HH + h)*WW + w_in)*CIN + g*CG + cin + ts*8)
            : zbuf + lane*8;
        load_lds16(src, dst + (rr*114 + 1 + ii*16)*CK);
    }
}

// 7 x-fragment LDS reads for tap (KH2,KW2) into XN (r3-verified swizzled path)
#define XL(XN, KH2, KW2)                                                    \
  {                                                                         \
    int sB_ = lk ^ (((2*(wr + (KH2)) + l15 + (KW2)) >> 1) & 3);             \
    const ushort* bb_ = xcur + ((wr + (KH2))*114 + l15 + (KW2))*CK + sB_*8; \
    _Pragma("unroll")                                                       \
    for (int n_ = 0; n_ < 7; ++n_)                                          \
      XN[n_] = *reinterpret_cast<const bf16x8*>(bb_ + n_*16*CK);            \
  }

// 4 w-fragment LDS reads for tap TAP2 (JIT: waited on by the MFMA cluster,
// leaving the 7 x-prefetch reads outstanding -> lgkmcnt(7))
#define WL(TAP2)                                                            \
  {                                                                         \
    const ushort* ab_ = wsb + ((TAP2)*COG + wm*64 + l15)*CK + sA*8;         \
    _Pragma("unroll")                                                       \
    for (int u_ = 0; u_ < 4; ++u_)                                          \
      wf[u_] = *reinterpret_cast<const bf16x8*>(ab_ + u_*16*CK);            \
  }

// 28 MFMAs on current-tap registers (operand-swapped: D rows = pixels)
#define MF(XC)                                                              \
    __builtin_amdgcn_s_setprio(1);                                          \
    _Pragma("unroll")                                                       \
    for (int u_ = 0; u_ < 4; ++u_)                                          \
      _Pragma("unroll")                                                     \
      for (int i_ = 0; i_ < 7; ++i_)                                        \
        acc[i_][u_] = __builtin_amdgcn_mfma_f32_16x16x32_bf16(              \
            XC[i_], wf[u_], acc[i_][u_], 0, 0, 0);                          \
    __builtin_amdgcn_s_setprio(0);

// ---- main kernel: r3 champion + intra-wave x-fragment prefetch ----
// Identical staging/swizzle/barrier structure to r3 (160us, verified). ONE
// structural change: next-tap x-fragments are read one tap ahead (xfA/xfB
// ping-pong, +28 VGPR), so each wave's LDS reads issue UNDER the previous
// MFMA cluster instead of serializing before it -> LDS pipe and MFMA pipe
// overlap. w-fragments load JIT (their lgkm wait keeps the 7 prefetch reads
// in flight). Plus r8's bijective XCD swizzle (FETCH 85->60MB) and r7's
// operand-swapped dwordx4 epilogue (both verified).
__global__ __launch_bounds__(512, 2) void k_conv(const ushort* __restrict__ xb,
                                                 const ushort* __restrict__ wb,
                                                 const float* __restrict__ bias,
                                                 float* __restrict__ out,
                                                 const ushort* __restrict__ zbuf) {
    __shared__ __align__(16) ushort xs[2][6*114*CK];     // 2 x 43776 B
    __shared__ __align__(16) ushort wsb[9*COG*CK];       // 73728 B (tot 161280)

    int orig = (blockIdx.x & 7) * 112 + (blockIdx.x >> 3);   // XCD swizzle
    int g   = orig / 448;
    int r   = orig % 448;
    int b   = r / 28;
    int q   = r % 28;
    int oh0 = q * 4;

    int tid  = threadIdx.x;
    int wave = tid >> 6;
    int lane = tid & 63;
    int wm   = wave >> 2;          // cout half (0..1), 64 couts
    int wr   = wave & 3;           // output row within quad (0..3)
    int l15  = lane & 15;
    int lk   = lane >> 4;
    int sA   = lk ^ ((l15 >> 1) & 3);    // weight-read slot

    // zero pad columns (w=0,113) of both x buffers
    for (int t = tid; t < 768; t += 512) {
        int buf = t / 384, r2 = t % 384;
        int rr = r2 / 64, wc = (r2 >> 5) & 1, ch = r2 & 31;
        xs[buf][(rr*114 + wc*113)*CK + ch] = 0;
    }

    // bias per lane: co = g*COG + wm*64 + u*16 + l15
    float bvreg[4];
#pragma unroll
    for (int u = 0; u < 4; ++u)
        bvreg[u] = bias[g*COG + wm*64 + u*16 + l15];

    f32x4 acc[7][4];
#pragma unroll
    for (int i = 0; i < 7; ++i)
#pragma unroll
        for (int u = 0; u < 4; ++u) acc[i][u] = f32x4{0.f,0.f,0.f,0.f};

    bf16x8 xfA[7], xfB[7], wf[4];

    // prologue: stage x chunk 0 + all 9 w taps of chunk 0; full drain once
    stage_x(xb, xs[0], zbuf, b, g, oh0, 0, wave, lane);
    stage_w_all(wb, wsb, g, 0, wave, lane);
    __syncthreads();

#pragma unroll 1
    for (int c = 0; c < NCHUNK; ++c) {
        const ushort* xcur = xs[c & 1];
        if (c + 1 < NCHUNK)
            stage_x(xb, xs[(c + 1) & 1], zbuf, b, g, oh0, (c + 1)*CK, wave, lane);

        // 9 taps, barrier-free; x prefetched 1 tap ahead, w JIT
        XL(xfA, 0, 0)
        XL(xfB, 0, 1)  WL(0)  MF(xfA)
        XL(xfA, 0, 2)  WL(1)  MF(xfB)
        XL(xfB, 1, 0)  WL(2)  MF(xfA)
        XL(xfA, 1, 1)  WL(3)  MF(xfB)
        XL(xfB, 1, 2)  WL(4)  MF(xfA)
        XL(xfA, 2, 0)  WL(5)  MF(xfB)
        XL(xfB, 2, 1)  WL(6)  MF(xfA)
        XL(xfA, 2, 2)  WL(7)  MF(xfB)
                       WL(8)  MF(xfA)

        // barrier 1: all waves done READING xs[c&1] + wsb (lgkm-only drain;
        // the x(c+1) global_load_lds prefetch stays in flight)
        __builtin_amdgcn_sched_barrier(0);
        asm volatile("s_waitcnt lgkmcnt(0)" ::: "memory");
        __builtin_amdgcn_s_barrier();

        if (c + 1 < NCHUNK)
            stage_w_all(wb, wsb, g, (c + 1)*CK, wave, lane);

        // barrier 2: full drain (w restage + the chunk-old x prefetch)
        __syncthreads();
    }

    // epilogue (r7-verified): acc[i][u] -> 28 dwordx4 stores, 4 contiguous px
    int oh = oh0 + wr;
#pragma unroll
    for (int u = 0; u < 4; ++u) {
        int co = g*COG + wm*64 + u*16 + l15;
        float bv = bvreg[u];
        float* obase = out + (((size_t)(b*CIN + co)*HH + oh)*WW + lk*4);
#pragma unroll
        for (int i = 0; i < 7; ++i) {
            f32x4 v;
            v[0] = acc[i][u][0] + bv;
            v[1] = acc[i][u][1] + bv;
            v[2] = acc[i][u][2] + bv;
            v[3] = acc[i][u][3] + bv;
            *reinterpret_cast<f32x4*>(obase + i*16) = v;
        }
    }
}

// ---- fallback: direct fp32 conv (used only if ws is too small) ----
__global__ __launch_bounds__(128) void k_direct(const float* __restrict__ x,
                                                const float* __restrict__ w,
                                                const float* __restrict__ bias,
                                                float* __restrict__ out) {
    int bid = blockIdx.x;          // B*Cout*H
    int oh  = bid % HH;
    int t   = bid / HH;
    int co  = t % CIN;
    int b   = t / CIN;
    int ow  = threadIdx.x;
    if (ow >= WW) return;
    int g = co / COG;
    float s = bias[co];
    const float* wp = w + (size_t)co*CG*9;
    const float* xp = x + ((size_t)b*CIN + g*CG)*HH*WW;
    for (int ci = 0; ci < CG; ++ci) {
        const float* xr = xp + (size_t)ci*HH*WW;
        const float* wr_ = wp + ci*9;
#pragma unroll
        for (int kh = 0; kh < 3; ++kh) {
            int ih = oh + kh - 1;
            if (ih < 0 || ih >= HH) continue;
#pragma unroll
            for (int kw = 0; kw < 3; ++kw) {
                int iw = ow + kw - 1;
                if (iw < 0 || iw >= WW) continue;
                s += xr[ih*WW + iw] * wr_[kh*3 + kw];
            }
        }
    }
    out[(((size_t)b*CIN + co)*HH + oh)*WW + ow] = s;
}

extern "C" void kernel_launch(void* const* d_in, const int* in_sizes, int n_in,
                              void* d_out, int out_size, void* d_ws, size_t ws_size,
                              hipStream_t stream) {
    const float* x    = (const float*)d_in[0];
    const float* w    = (const float*)d_in[1];
    const float* bias = (const float*)d_in[2];
    float* out        = (float*)d_out;

    if (ws_size >= WS_NEED) {
        ushort* wb   = (ushort*)d_ws;
        ushort* zb   = (ushort*)((char*)d_ws + ZBUF_OFF);
        ushort* xbuf = (ushort*)((char*)d_ws + XB_OFF);
        hipMemsetAsync(zb, 0, ZBUF_BYTES, stream);
        k_wcvt<<<1152, 256, 0, stream>>>(w, wb);
        k_xcvt<<<BATCH*HH*4, 256, 0, stream>>>(x, xbuf);
        k_conv<<<896, 512, 0, stream>>>(xbuf, wb, bias, out, zb);
    } else {
        k_direct<<<BATCH*CIN*HH, 128, 0, stream>>>(x, w, bias, out);
    }
}

// Round 11
// 241.323 us; speedup vs baseline: 1.9792x; 1.0070x over previous
//
#include <hip/hip_runtime.h>
#include <hip/hip_bf16.h>
#include <stdint.h>

#define BATCH 16
#define CIN   256
#define HH    112
#define WW    112
#define GROUPS 2
#define CG    128   // cin per group
#define COG   128   // cout per group
#define CK    32    // cin chunk per K-step
#define NCHUNK 4

typedef __bf16 bf16x8 __attribute__((ext_vector_type(8)));
typedef float  f32x4  __attribute__((ext_vector_type(4)));

// ---- workspace layout ----
#define WB_BYTES   (GROUPS*3*3*COG*CG*2)        // 589824
#define ZBUF_OFF   WB_BYTES
#define ZBUF_BYTES 8192
#define XB_OFF     (ZBUF_OFF + ZBUF_BYTES)      // 598016
#define XB_BYTES   ((size_t)BATCH*HH*WW*CIN*2)  // 102760448
#define WS_NEED    ((size_t)XB_OFF + XB_BYTES)  // 103358464

__device__ inline void load_lds16(const void* g, void* l) {
    __builtin_amdgcn_global_load_lds(
        (const __attribute__((address_space(1))) void*)g,
        (__attribute__((address_space(3))) void*)l, 16, 0, 0);
}

// ---- pre-pass 1: weights OIHW fp32 -> lane-major reg-load layout ----
// wb[g][chunk][tap][wm][u][lk][l15][c8]: one wave's (chunk,tap,wm,u) fragment
// load is 64 lanes x 16B CONTIGUOUS (lane = lk*16+l15). 4KB per (g,c,tap,wm).
__global__ __launch_bounds__(256) void k_wcvt(const float* __restrict__ w,
                                              ushort* __restrict__ wb) {
    int i = blockIdx.x * 256 + threadIdx.x;   // 294912 total
    int c8  = i & 7;
    int l15 = (i >> 3) & 15;
    int lk  = (i >> 7) & 3;
    int u   = (i >> 9) & 3;
    int wm  = (i >> 11) & 1;
    int hi  = i >> 12;            // 0..71
    int tap = hi % 9;
    int gch = hi / 9;             // 0..7
    int chunk = gch & 3, g = gch >> 2;
    int co = wm*64 + u*16 + l15;
    int ci = chunk*32 + lk*8 + c8;
    int src = ((g*COG + co)*CG + ci)*9 + tap;
    __hip_bfloat16 v = __float2bfloat16(w[src]);
    wb[i] = *reinterpret_cast<ushort*>(&v);
}

// ---- pre-pass 2: x NCHW fp32 -> NHWC bf16 (LDS transpose) ----
#define XPAD 113
__global__ __launch_bounds__(256) void k_xcvt(const float* __restrict__ x,
                                              ushort* __restrict__ xb) {
    __shared__ float tile[64 * XPAD];
    int bid = blockIdx.x;            // 16*112*4 = 7168
    int cc  = bid & 3;               // chunk of 64 channels
    int h   = (bid >> 2) % HH;
    int b   = bid / (4 * HH);
    int tid = threadIdx.x;

    const float* src = x + ((size_t)(b*CIN + cc*64) * HH + h) * WW;
    for (int tt = tid; tt < 64*28; tt += 256) {
        int c = tt / 28, v = tt % 28;
        float4 f = *reinterpret_cast<const float4*>(src + (size_t)c*HH*WW + v*4);
        float* d = &tile[c*XPAD + v*4];
        d[0]=f.x; d[1]=f.y; d[2]=f.z; d[3]=f.w;
    }
    __syncthreads();

    if (tid < 224) {
        int w = tid >> 1, half = tid & 1;
        ushort o[32];
#pragma unroll
        for (int j = 0; j < 32; ++j) {
            __hip_bfloat16 v = __float2bfloat16(tile[(half*32 + j)*XPAD + w]);
            o[j] = *reinterpret_cast<ushort*>(&v);
        }
        ushort* dst = xb + (((size_t)(b*HH + h)*WW + w)*CIN + cc*64 + half*32);
        const uint4* o4 = reinterpret_cast<const uint4*>(o);
        uint4* d4 = reinterpret_cast<uint4*>(dst);
        d4[0]=o4[0]; d4[1]=o4[1]; d4[2]=o4[2]; d4[3]=o4[3];
    }
}

// ---- one x-stage slot (real task t<42, else dummy; 6 per thread uniform) ----
__device__ inline void xpre48(const ushort* __restrict__ xb, ushort* dstbuf,
                              ushort* dump, const ushort* __restrict__ zbuf,
                              int b, int g, int oh0, int cin, int t, int lane) {
    if (t < 42) {
        int rr = t / 7, ii = t % 7;
        int h  = oh0 - 1 + rr;
        int qv = lane >> 2;
        int w_in = ii*16 + qv;
        int ts = (lane & 3) ^ (((2*rr + 1 + qv) >> 1) & 3);
        const ushort* src = (h >= 0 && h < HH)
            ? xb + (((size_t)(b*HH + h)*WW + w_in)*CIN + g*CG + cin + ts*8)
            : zbuf + lane*8;
        load_lds16(src, dstbuf + (rr*114 + 1 + ii*16)*CK);
    } else {
        load_lds16(zbuf + lane*8, dump);
    }
}

// 7 x-fragment LDS reads for tap (KH2,KW2) from buffer BUF into XN
#define XLB(BUF, XN, KH2, KW2)                                              \
  {                                                                         \
    int sB_ = lk ^ (((2*(wr + (KH2)) + l15 + (KW2)) >> 1) & 3);             \
    const ushort* bb_ = (BUF) + ((wr + (KH2))*114 + l15 + (KW2))*CK + sB_*8;\
    _Pragma("unroll")                                                       \
    for (int n_ = 0; n_ < 7; ++n_)                                          \
      XN[n_] = *reinterpret_cast<const bf16x8*>(bb_ + n_*16*CK);            \
  }

// 4 coalesced global wf loads for (chunk CN, tap TN) into WN
// base block = ((g4+CN)*9+TN)*2+wm, 4KB each; u at +1KB imm offsets
#define WLG(WN, CN, TN)                                                     \
  {                                                                         \
    const ushort* wp_ = wlane + ((size_t)((((g4 + (CN))*9 + (TN))*2 + wm)) << 11); \
    _Pragma("unroll")                                                       \
    for (int u_ = 0; u_ < 4; ++u_)                                          \
      WN[u_] = *reinterpret_cast<const bf16x8*>(wp_ + (u_ << 9));           \
  }

// 28 MFMAs on current-tap registers (operand-swapped: D rows = pixels)
#define MF(XC)                                                              \
    __builtin_amdgcn_sched_barrier(0);                                      \
    __builtin_amdgcn_s_setprio(1);                                          \
    _Pragma("unroll")                                                       \
    for (int u_ = 0; u_ < 4; ++u_)                                          \
      _Pragma("unroll")                                                     \
      for (int i_ = 0; i_ < 7; ++i_)                                        \
        acc[i_][u_] = __builtin_amdgcn_mfma_f32_16x16x32_bf16(              \
            XC[i_], wfC[u_], acc[i_][u_], 0, 0, 0);                         \
    __builtin_amdgcn_s_setprio(0);

#define ROT4                                                                \
    _Pragma("unroll")                                                       \
    for (int u_ = 0; u_ < 4; ++u_) wfC[u_] = wfN[u_];

// ---- main kernel: x in LDS (verified swizzle), w global->reg coalesced ----
// LDS-pipe load per tap: 88 -> 56 b128/CU (672 cyc < MFMA 1086 -> MFMA-bound).
// Both operands prefetched 1 tap ahead: wf via vmem (vmcnt), xf via LDS
// ping-pong (lgkm) -> each MFMA cluster covers the next tap's loads. ONE
// barrier per chunk. stage_w/wsb/its drains are gone. Register budget:
// 112 AGPR + 88 frag VGPR (fits 2 waves/SIMD; r5/r9 overflow avoided).
__global__ __launch_bounds__(512, 2) void k_conv(const ushort* __restrict__ xb,
                                                 const ushort* __restrict__ wb,
                                                 const float* __restrict__ bias,
                                                 float* __restrict__ out,
                                                 const ushort* __restrict__ zbuf) {
    __shared__ __align__(16) ushort xs[2][6*114*CK];     // 2 x 43776 B
    __shared__ __align__(16) ushort dump[512];           // pad sink (1 KB)

    int orig = (blockIdx.x & 7) * 112 + (blockIdx.x >> 3);   // XCD swizzle
    int g   = orig / 448;
    int r   = orig % 448;
    int b   = r / 28;
    int q   = r % 28;
    int oh0 = q * 4;

    int tid  = threadIdx.x;
    int wave = tid >> 6;
    int lane = tid & 63;
    int wm   = wave >> 2;          // cout half (0..1), 64 couts
    int wr   = wave & 3;           // output row within quad (0..3)
    int l15  = lane & 15;
    int lk   = lane >> 4;
    int g4   = g * 4;
    const ushort* wlane = wb + lane*8;   // per-lane 16B slot in wf blocks

    // zero pad columns (w=0,113) of both x buffers
    for (int t = tid; t < 768; t += 512) {
        int buf = t / 384, r2 = t % 384;
        int rr = r2 / 64, wc = (r2 >> 5) & 1, ch = r2 & 31;
        xs[buf][(rr*114 + wc*113)*CK + ch] = 0;
    }

    f32x4 acc[7][4];
#pragma unroll
    for (int i = 0; i < 7; ++i)
#pragma unroll
        for (int u = 0; u < 4; ++u) acc[i][u] = f32x4{0.f,0.f,0.f,0.f};

    bf16x8 xfA[7], xfB[7], wfC[4], wfN[4];

    // prologue: stage x chunk 0; load wf(c0,t0); full drain; first xf
    for (int k2 = 0; k2 < 6; ++k2)
        xpre48(xb, xs[0], dump, zbuf, b, g, oh0, 0, wave + 8*k2, lane);
    WLG(wfC, 0, 0)
    asm volatile("s_waitcnt vmcnt(0)" ::: "memory");
    __builtin_amdgcn_s_barrier();
    XLB(xs[0], xfA, 0, 0)

#pragma unroll 1
    for (int c = 0; c < NCHUNK; ++c) {
        const ushort* xcur = xs[c & 1];
        ushort* xnxt = xs[(c + 1) & 1];
        // stage next chunk's x (6 vmem/thread, uniform)
        if (c + 1 < NCHUNK)
            for (int k2 = 0; k2 < 6; ++k2)
                xpre48(xb, xnxt, dump, zbuf, b, g, oh0, (c + 1)*CK,
                       wave + 8*k2, lane);

        WLG(wfN, c, 1)      XLB(xcur, xfB, 0, 1)   MF(xfA)  ROT4
        WLG(wfN, c, 2)      XLB(xcur, xfA, 0, 2)   MF(xfB)  ROT4
        WLG(wfN, c, 3)      XLB(xcur, xfB, 1, 0)   MF(xfA)  ROT4
        WLG(wfN, c, 4)      XLB(xcur, xfA, 1, 1)   MF(xfB)  ROT4
        WLG(wfN, c, 5)      XLB(xcur, xfB, 1, 2)   MF(xfA)  ROT4
        WLG(wfN, c, 6)      XLB(xcur, xfA, 2, 0)   MF(xfB)  ROT4
        WLG(wfN, c, 7)      XLB(xcur, xfB, 2, 1)   MF(xfA)  ROT4
        WLG(wfN, c, 8)      XLB(xcur, xfA, 2, 2)   MF(xfB)  ROT4
        WLG(wfN, c + 1, 0)                         MF(xfA)  ROT4
        // (c=3: WLG reads 16B past wb into zbuf -- in-bounds, value unused)

        if (c + 1 < NCHUNK) {
            // publish xs[c+1]: own xf reads done (lgkm), all waves arrive,
            // then drain own stage loads (queue: [stage6][wf...]; vmcnt(4)
            // leaves only the 4 newest wf loads in flight)
            asm volatile("s_waitcnt lgkmcnt(0)" ::: "memory");
            __builtin_amdgcn_s_barrier();
            asm volatile("s_waitcnt vmcnt(4)" ::: "memory");
            XLB(xnxt, xfA, 0, 0)
        }
    }

    // epilogue (r7-verified): acc[i][u] -> 28 dwordx4 stores, 4 contiguous px
    int oh = oh0 + wr;
#pragma unroll
    for (int u = 0; u < 4; ++u) {
        int co = g*COG + wm*64 + u*16 + l15;
        float bv = bias[co];
        float* obase = out + (((size_t)(b*CIN + co)*HH + oh)*WW + lk*4);
#pragma unroll
        for (int i = 0; i < 7; ++i) {
            f32x4 v;
            v[0] = acc[i][u][0] + bv;
            v[1] = acc[i][u][1] + bv;
            v[2] = acc[i][u][2] + bv;
            v[3] = acc[i][u][3] + bv;
            *reinterpret_cast<f32x4*>(obase + i*16) = v;
        }
    }
}

// ---- fallback: direct fp32 conv (used only if ws is too small) ----
__global__ __launch_bounds__(128) void k_direct(const float* __restrict__ x,
                                                const float* __restrict__ w,
                                                const float* __restrict__ bias,
                                                float* __restrict__ out) {
    int bid = blockIdx.x;          // B*Cout*H
    int oh  = bid % HH;
    int t   = bid / HH;
    int co  = t % CIN;
    int b   = t / CIN;
    int ow  = threadIdx.x;
    if (ow >= WW) return;
    int g = co / COG;
    float s = bias[co];
    const float* wp = w + (size_t)co*CG*9;
    const float* xp = x + ((size_t)b*CIN + g*CG)*HH*WW;
    for (int ci = 0; ci < CG; ++ci) {
        const float* xr = xp + (size_t)ci*HH*WW;
        const float* wr_ = wp + ci*9;
#pragma unroll
        for (int kh = 0; kh < 3; ++kh) {
            int ih = oh + kh - 1;
            if (ih < 0 || ih >= HH) continue;
#pragma unroll
            for (int kw = 0; kw < 3; ++kw) {
                int iw = ow + kw - 1;
                if (iw < 0 || iw >= WW) continue;
                s += xr[ih*WW + iw] * wr_[kh*3 + kw];
            }
        }
    }
    out[(((size_t)b*CIN + co)*HH + oh)*WW + ow] = s;
}

extern "C" void kernel_launch(void* const* d_in, const int* in_sizes, int n_in,
                              void* d_out, int out_size, void* d_ws, size_t ws_size,
                              hipStream_t stream) {
    const float* x    = (const float*)d_in[0];
    const float* w    = (const float*)d_in[1];
    const float* bias = (const float*)d_in[2];
    float* out        = (float*)d_out;

    if (ws_size >= WS_NEED) {
        ushort* wb   = (ushort*)d_ws;
        ushort* zb   = (ushort*)((char*)d_ws + ZBUF_OFF);
        ushort* xbuf = (ushort*)((char*)d_ws + XB_OFF);
        hipMemsetAsync(zb, 0, ZBUF_BYTES, stream);
        k_wcvt<<<1152, 256, 0, stream>>>(w, wb);
        k_xcvt<<<BATCH*HH*4, 256, 0, stream>>>(x, xbuf);
        k_conv<<<896, 512, 0, stream>>>(xbuf, wb, bias, out, zb);
    } else {
        k_direct<<<BATCH*CIN*HH, 128, 0, stream>>>(x, w, bias, out);
    }
}